// Round 8
// baseline (256.915 us; speedup 1.0000x reference)
//
#include <hip/hip_runtime.h>

// GNN: 2x GCNConv(relu) + mean-pool + MLP head.
// Sizes fixed: N=50000, E=800000, F_IN=256, H=64, NG=64, NC=4.
//
// R9: hs/hb bf16, f32 accumulate. R11: dual-edge packed gather.
// R13: GEMMs on bf16 MFMA, split-bf16 hi/lo, swizzled LDS.
// R15: poolhead fusion regressed BUT gave exact decomposition:
//      pool+head1+head2 = 2.6us total, dispatch overhead ~0.
// R16: gemm2 fused into agg1 (free) -> kept.
// R17/R18/R19: agg rewrites all converge at 42.5us, FETCH 33MB invariant
//      -> random-line TCC-fill wall (2 lines/edge, bf16-irreducible).
// R20 (this round): gemm1 drops the lo-planes (pure-bf16 MFMA).
//      Rationale: hs storage is bf16 anyway (2^-9 grid); hi-only K=256
//      matmul error ~0.14% rel = same order as storage error. Halves
//      staging VALU, LDS 48->24KB, MFMAs 3->1 per tile. absmax expected
//      ~1e-3 (was 4.88e-4).

#define TPB 256
#define CHUNK_A 4096
#define BCAP 4608          // per-bucket staging capacity (mean 4096, +8 sigma)

typedef unsigned short bfu;
typedef __attribute__((ext_vector_type(8))) short s16x8;
typedef __attribute__((ext_vector_type(4))) float f32x4;

__device__ __forceinline__ float bf2f(bfu u) {
    union { unsigned u32; float f; } c; c.u32 = ((unsigned)u) << 16; return c.f;
}
__device__ __forceinline__ bfu f2bf(float f) {
    union { float f; unsigned u; } c; c.f = f;
    unsigned r = 0x7FFFu + ((c.u >> 16) & 1u);     // round-to-nearest-even
    return (bfu)((c.u + r) >> 16);
}
__device__ __forceinline__ float blo(unsigned w) {
    union { unsigned u32; float f; } c; c.u32 = w << 16; return c.f;
}
__device__ __forceinline__ float bhi(unsigned w) {
    union { unsigned u32; float f; } c; c.u32 = w & 0xFFFF0000u; return c.f;
}

// ---------------- pass A: chunked bucket staging ----------------
// packed edge: (src<<8) | (dst & 255); requires n <= 65536, nbuck <= 256.

__global__ __launch_bounds__(TPB) void k_passA(const int* __restrict__ srcv,
                                               const int* __restrict__ dstv, int E,
                                               int* __restrict__ gcur,
                                               int* __restrict__ staged, int nbuck) {
    __shared__ int pk[CHUNK_A];
    __shared__ int hist[256];
    __shared__ int ebase[256];
    __shared__ int gbase[256];
    __shared__ int lcur[256];
    int t = threadIdx.x;
    int e0 = blockIdx.x * CHUNK_A;
    int e1 = e0 + CHUNK_A; if (e1 > E) e1 = E;

    hist[t] = 0; lcur[t] = 0;
    __syncthreads();
    for (int i = e0 + t; i < e1; i += TPB) atomicAdd(&hist[dstv[i] >> 8], 1);
    __syncthreads();
    int v = hist[t];
    ebase[t] = v;
    __syncthreads();
    for (int off = 1; off < 256; off <<= 1) {
        int u = (t >= off) ? ebase[t - off] : 0;
        __syncthreads();
        ebase[t] += u;
        __syncthreads();
    }
    ebase[t] -= v;
    if (t < nbuck && v > 0) gbase[t] = t * BCAP + atomicAdd(&gcur[t], v);
    __syncthreads();
    for (int i = e0 + t; i < e1; i += TPB) {
        int d = dstv[i];
        int s = srcv[i];
        int b = d >> 8;
        int r = atomicAdd(&lcur[b], 1);
        pk[ebase[b] + r] = (s << 8) | (d & 255);
    }
    __syncthreads();
    int wave = t >> 6, lane = t & 63;
    for (int b = wave; b < nbuck; b += 4) {
        int c = hist[b];
        int lb = ebase[b];
        int gb = gbase[b];
        for (int j = lane; j < c; j += 64) staged[gb + j] = pk[lb + j];
    }
}

// ---------------- pass B: per-bucket node sort + csr_off + dinv ----------------

__global__ __launch_bounds__(TPB) void k_passB(const int* __restrict__ staged,
                                               const int* __restrict__ gcur,
                                               int* __restrict__ csr_off,
                                               int* __restrict__ csr_src,
                                               float* __restrict__ dinv,
                                               int n, int nbuck) {
    __shared__ int pk[BCAP];
    __shared__ int soff[256];
    __shared__ int hist[256];
    __shared__ int nbase[256];
    __shared__ int cur[256];
    int b = blockIdx.x;
    int n0 = b << 8;
    int n1 = n0 + 256; if (n1 > n) n1 = n;
    int cnt = gcur[b];
    int t = threadIdx.x;

    int cv = (t < nbuck) ? gcur[t] : 0;
    soff[t] = cv;
    hist[t] = 0; cur[t] = 0;
    __syncthreads();
    for (int off = 1; off < 256; off <<= 1) {
        int u = (t >= off) ? soff[t - off] : 0;
        __syncthreads();
        soff[t] += u;
        __syncthreads();
    }
    int base = soff[b] - cnt;   // exclusive prefix at bucket b

    for (int i = t; i < cnt; i += TPB) pk[i] = staged[b * BCAP + i];
    __syncthreads();
    for (int i = t; i < cnt; i += TPB) atomicAdd(&hist[pk[i] & 255], 1);
    __syncthreads();
    int v = hist[t];
    nbase[t] = v;
    __syncthreads();
    for (int off = 1; off < 256; off <<= 1) {
        int u = (t >= off) ? nbase[t - off] : 0;
        __syncthreads();
        nbase[t] += u;
        __syncthreads();
    }
    nbase[t] -= v;
    if (n0 + t < n1) {
        csr_off[n0 + t] = base + nbase[t];
        dinv[n0 + t] = rsqrtf((float)(v + 1));   // +1 self loop
    }
    if (b == nbuck - 1 && t == 0) csr_off[n] = base + cnt;
    __syncthreads();
    for (int i = t; i < cnt; i += TPB) {
        int p = pk[i];
        int dloc = p & 255;
        int r = atomicAdd(&cur[dloc], 1);
        csr_src[base + nbase[dloc] + r] = p >> 8;
    }
}

// ---------------- GEMM (MFMA, pure bf16): C[r][j] = dinv[r]*sum_k A[r][k]*W[k][j] ----------------
// Block = 128 rows x 64 cols, 4 waves; wave = 32 rows x 64 cols
// (2 row-tiles x 4 col-tiles of 16x16, K-step 32). K-chunk 64 in LDS.
// R20: hi-only bf16 (no lo planes) — storage is bf16 anyway; hi-only
// matmul error (~2^-10*sqrt(2K) rel) ~= bf16 storage error. 24KB LDS.
// LDS XOR swizzle: element k ^ ((rc&7)<<3), 16B-granule permutation.
// C/D map (m89-verified): col=lane&15, row=(lane>>4)*4+reg.

__device__ __forceinline__ int swz(int rc, int k) {
    return rc * 64 + (k ^ ((rc & 7) << 3));
}

__global__ __launch_bounds__(TPB) void k_gemm1(const float* __restrict__ A,
                                               const float* __restrict__ W,
                                               const float* __restrict__ dinv,
                                               bfu* __restrict__ C, int n) {
    const int K = 256;
    __shared__ __align__(16) ushort Ah[128 * 64];
    __shared__ __align__(16) ushort Bh[64 * 64];

    const int t = threadIdx.x;
    const int wave = t >> 6, lane = t & 63;
    const int rbase = blockIdx.x * 128;

    f32x4 acc[2][4];
#pragma unroll
    for (int i = 0; i < 2; i++)
#pragma unroll
        for (int j = 0; j < 4; j++) acc[i][j] = {0.f, 0.f, 0.f, 0.f};

    for (int kc = 0; kc < K; kc += 64) {
        // ---- stage B: W chunk [64k x 64c] -> transposed bf16 ----
        {
            int c = t & 63;
            int kg = (t >> 6) << 4;   // 16 k's per wave
#pragma unroll
            for (int q = 0; q < 4; q++) {
                ushort4 h4;
#pragma unroll
                for (int j = 0; j < 4; j++) {
                    ((bfu*)&h4)[j] = f2bf(W[(size_t)(kc + kg + q * 4 + j) * 64 + c]);
                }
                *(ushort4*)&Bh[swz(c, kg + q * 4)] = h4;
            }
        }
        // ---- stage A chunk [128r x 64k] ----
        {
#pragma unroll
            for (int q = 0; q < 8; q++) {
                int idx = q * 256 + t;
                int row = idx >> 4;
                int k4 = (idx & 15) << 2;
                int r = rbase + row;
                float4 xv = make_float4(0.f, 0.f, 0.f, 0.f);
                if (r < n) xv = *(const float4*)&A[(size_t)r * K + kc + k4];
                ushort4 h4;
                ((bfu*)&h4)[0] = f2bf(xv.x);
                ((bfu*)&h4)[1] = f2bf(xv.y);
                ((bfu*)&h4)[2] = f2bf(xv.z);
                ((bfu*)&h4)[3] = f2bf(xv.w);
                *(ushort4*)&Ah[swz(row, k4)] = h4;
            }
        }
        __syncthreads();

        // ---- MFMA compute ----
        const int rl = lane & 15;            // M/N index within tile
        const int kg8 = (lane >> 4) << 3;    // k offset of this lane group
#pragma unroll
        for (int ks = 0; ks < 2; ks++) {
            int k0 = ks * 32 + kg8;
            s16x8 a_h[2], b_h[4];
#pragma unroll
            for (int rt = 0; rt < 2; rt++) {
                int row = wave * 32 + rt * 16 + rl;
                a_h[rt] = *(const s16x8*)&Ah[swz(row, k0)];
            }
#pragma unroll
            for (int ct = 0; ct < 4; ct++) {
                int cc = ct * 16 + rl;
                b_h[ct] = *(const s16x8*)&Bh[swz(cc, k0)];
            }
#pragma unroll
            for (int rt = 0; rt < 2; rt++)
#pragma unroll
                for (int ct = 0; ct < 4; ct++) {
                    acc[rt][ct] = __builtin_amdgcn_mfma_f32_16x16x32_bf16(
                        a_h[rt], b_h[ct], acc[rt][ct], 0, 0, 0);
                }
        }
        __syncthreads();
    }

    // ---- epilogue ----
    const int rl = lane & 15;
    const int rq = (lane >> 4) << 2;
#pragma unroll
    for (int rt = 0; rt < 2; rt++) {
#pragma unroll
        for (int reg = 0; reg < 4; reg++) {
            int r = rbase + wave * 32 + rt * 16 + rq + reg;
            if (r < n) {
                float d = dinv[r];
#pragma unroll
                for (int ct = 0; ct < 4; ct++) {
                    C[(size_t)r * 64 + ct * 16 + rl] = f2bf(acc[rt][ct][reg] * d);
                }
            }
        }
    }
}

// ---------------- Aggregation (R19): wide row gather (dwordx4) ----------------
// Wave = 1 node. Lane map: g = lane>>3 (row slot 0..7), c = lane&7
// (8-feature chunk). One dwordx4 gather = 8 neighbor rows x 128B
// (16B/lane). Index load csr_src[p0+base+g]: broadcast in 8-lane groups,
// NO shfl. Feature totals via 3 shfl_xor rounds once per node.
// FUSE: per-wave 64x64 W2 matmul on the relu'd row (gemm2 fusion, R16).

__device__ __forceinline__ void acc_u4(float* acc, uint4 q) {
    acc[0] += blo(q.x); acc[1] += bhi(q.x);
    acc[2] += blo(q.y); acc[3] += bhi(q.y);
    acc[4] += blo(q.z); acc[5] += bhi(q.z);
    acc[6] += blo(q.w); acc[7] += bhi(q.w);
}

template <bool FUSE>
__global__ __launch_bounds__(TPB) void k_agg(const bfu* __restrict__ hs,
                                             const int* __restrict__ csr_off,
                                             const int* __restrict__ csr_src,
                                             const float* __restrict__ dinv,
                                             const float* __restrict__ bias,
                                             const float* __restrict__ W2,
                                             bfu* __restrict__ out, int n) {
    __shared__ float rowbuf[4][64];
    int wv = threadIdx.x >> 6;
    int node = blockIdx.x * 4 + wv;
    int lane = threadIdx.x & 63;
    int g = lane >> 3;             // row slot within batch
    int c = lane & 7;              // feature chunk (feats c*8 .. c*8+7)
    if (node >= n) return;
    int p0 = csr_off[node];
    int p1 = csr_off[node + 1];
    int deg = p1 - p0;
    float d = dinv[node];          // issue early, needed late

    // self row (hot line), added once after the cross-lane reduction
    uint4 selfv = *(const uint4*)(hs + (size_t)node * 64 + c * 8);

    float acc[8];
#pragma unroll
    for (int j = 0; j < 8; j++) acc[j] = 0.f;

    for (int base = 0; base < deg; base += 16) {
        int rem = deg - base;
        int li0 = p0 + base + g;
        if (rem > 8) {
            // slots 0..7 all valid; slots 8..15 predicated
            int li1 = li0 + 8;
            int idx0 = csr_src[li0];
            int idx1 = csr_src[li1 < p1 ? li1 : p0];
            bool v1 = (8 + g) < rem;
            uint4 q0 = *(const uint4*)(hs + (size_t)idx0 * 64 + c * 8);
            uint4 q1 = *(const uint4*)(hs + (size_t)(v1 ? idx1 : node) * 64 + c * 8);
            if (!v1) q1 = make_uint4(0u, 0u, 0u, 0u);
            acc_u4(acc, q0);
            acc_u4(acc, q1);
        } else {
            bool v0 = g < rem;
            int idx0 = csr_src[li0 < p1 ? li0 : p0];
            uint4 q0 = *(const uint4*)(hs + (size_t)(v0 ? idx0 : node) * 64 + c * 8);
            if (!v0) q0 = make_uint4(0u, 0u, 0u, 0u);
            acc_u4(acc, q0);
        }
    }

    // reduce across row-slot groups (lane bits 3,4,5)
#pragma unroll
    for (int j = 0; j < 8; j++) {
        acc[j] += __shfl_xor(acc[j], 8);
        acc[j] += __shfl_xor(acc[j], 16);
        acc[j] += __shfl_xor(acc[j], 32);
    }
    // self loop (each lane keeps a consistent replicated copy)
    acc_u4(acc, selfv);

    float4 b0 = *(const float4*)&bias[c * 8];
    float4 b1 = *(const float4*)&bias[c * 8 + 4];
    float v[8];
    v[0] = fmaxf(d * acc[0] + b0.x, 0.f);
    v[1] = fmaxf(d * acc[1] + b0.y, 0.f);
    v[2] = fmaxf(d * acc[2] + b0.z, 0.f);
    v[3] = fmaxf(d * acc[3] + b0.w, 0.f);
    v[4] = fmaxf(d * acc[4] + b1.x, 0.f);
    v[5] = fmaxf(d * acc[5] + b1.y, 0.f);
    v[6] = fmaxf(d * acc[6] + b1.z, 0.f);
    v[7] = fmaxf(d * acc[7] + b1.w, 0.f);

    if (!FUSE) {
        if (g == 0) {   // lanes 0..7 write the 128B row
            uint4 o;
            o.x = (unsigned)f2bf(v[0]) | ((unsigned)f2bf(v[1]) << 16);
            o.y = (unsigned)f2bf(v[2]) | ((unsigned)f2bf(v[3]) << 16);
            o.z = (unsigned)f2bf(v[4]) | ((unsigned)f2bf(v[5]) << 16);
            o.w = (unsigned)f2bf(v[6]) | ((unsigned)f2bf(v[7]) << 16);
            *(uint4*)(out + (size_t)node * 64 + c * 8) = o;
        }
    } else {
        // fused gemm2: out[node][lane] = f2bf(d * sum_k row[k] * W2[k][lane])
        if (g == 0) {
            *(float4*)&rowbuf[wv][c * 8]     = make_float4(v[0], v[1], v[2], v[3]);
            *(float4*)&rowbuf[wv][c * 8 + 4] = make_float4(v[4], v[5], v[6], v[7]);
        }
        __builtin_amdgcn_wave_barrier();   // ds_write before ds_read (same wave: HW in-order)
        float a = 0.f;
#pragma unroll 16
        for (int k = 0; k < 64; k++) a += rowbuf[wv][k] * W2[k * 64 + lane];
        out[(size_t)node * 64 + lane] = f2bf(d * a);
    }
}

// ---------------- Pool: sorted batch; uniform-chunk fast path (bf16 reads) ----------------

__global__ __launch_bounds__(TPB) void k_pool(const bfu* __restrict__ h,
                                              const int* __restrict__ batch, int n,
                                              float* __restrict__ gsum,
                                              int* __restrict__ gcnt) {
    const int CH = 16;
    int wid = blockIdx.x * 4 + (threadIdx.x >> 6);
    int lane = threadIdx.x & 63;
    int i0 = wid * CH;
    if (i0 >= n) return;
    int i1 = i0 + CH; if (i1 > n) i1 = n;
    int g0 = batch[i0];
    int g1 = batch[i1 - 1];
    if (g0 == g1) {
        float acc = 0.f;
#pragma unroll
        for (int i = 0; i < CH; i++) {
            int idx = i0 + i;
            if (idx < i1) acc += bf2f(h[(size_t)idx * 64 + lane]);
        }
        atomicAdd(&gsum[g0 * 64 + lane], acc);
        if (lane == 0) atomicAdd(&gcnt[g0], i1 - i0);
    } else {
        int cur = g0;
        float acc = 0.f;
        int cnt = 0;
        for (int i = i0; i < i1; i++) {
            int g = batch[i];
            if (g != cur) {
                atomicAdd(&gsum[cur * 64 + lane], acc);
                if (lane == 0) atomicAdd(&gcnt[cur], cnt);
                acc = 0.f; cnt = 0; cur = g;
            }
            acc += bf2f(h[(size_t)i * 64 + lane]);
            cnt++;
        }
        atomicAdd(&gsum[cur * 64 + lane], acc);
        if (lane == 0) atomicAdd(&gcnt[cur], cnt);
    }
}

// ---------------- Head, stage 1 ----------------

__global__ __launch_bounds__(TPB) void k_head1(const float* __restrict__ gsum,
                                               const int* __restrict__ gcnt,
                                               const float* __restrict__ fc1w,
                                               const float* __restrict__ fc1b,
                                               float* __restrict__ z) {
    int t = threadIdx.x;
    int g = blockIdx.x * 2 + (t >> 7);
    int o = t & 127;
    int c = gcnt[g]; if (c < 1) c = 1;
    float inv = 1.0f / (float)c;
    float a = fc1b[o];
#pragma unroll 16
    for (int j = 0; j < 64; j++) {
        float pj = gsum[g * 64 + j] * inv;
        a += pj * fc1w[j * 128 + o];
    }
    z[g * 128 + o] = fmaxf(a, 0.f);
}

// ---------------- Head, stage 2 ----------------

__global__ __launch_bounds__(TPB) void k_head2(const float* __restrict__ z,
                                               const float* __restrict__ fc2w,
                                               const float* __restrict__ fc2b,
                                               float* __restrict__ out) {
    int t = threadIdx.x;
    int g = t >> 2, c = t & 3;
    float a = fc2b[c];
#pragma unroll 16
    for (int o = 0; o < 128; o++) a += z[g * 128 + o] * fc2w[o * 4 + c];
    out[t] = a;
}

// ---------------- launch ----------------

extern "C" void kernel_launch(void* const* d_in, const int* in_sizes, int n_in,
                              void* d_out, int out_size, void* d_ws, size_t ws_size,
                              hipStream_t stream) {
    const float* x    = (const float*)d_in[0];
    const int*   ei   = (const int*)d_in[1];
    const int*   batch= (const int*)d_in[2];
    const float* W1   = (const float*)d_in[3];
    const float* b1   = (const float*)d_in[4];
    const float* W2   = (const float*)d_in[5];
    const float* b2   = (const float*)d_in[6];
    const float* fc1w = (const float*)d_in[7];
    const float* fc1b = (const float*)d_in[8];
    const float* fc2w = (const float*)d_in[9];
    const float* fc2b = (const float*)d_in[10];

    const int n = in_sizes[2];        // 50000
    const int E = in_sizes[1] / 2;    // 800000
    const int* srcv = ei;
    const int* dstv = ei + E;
    const int nbuck = (n + 255) >> 8; // 196 (must be <= 256)

    // workspace carve; zeroed region contiguous at front
    char* w = (char*)d_ws;
    int*   gcur   = (int*)w;            w += 256 * 4;
    int*   gcnt   = (int*)w;            w += 64 * 4;
    float* gsum   = (float*)w;          w += 64 * 64 * 4;
    size_t zbytes = (size_t)w - (size_t)d_ws;
    int*   csr_off= (int*)w;            w += (size_t)(n + 1) * 4;
    float* dinv   = (float*)w;          w += (size_t)n * 4;
    int*   csr_src= (int*)w;            w += (size_t)E * 4;
    int*   staged = (int*)w;            w += (size_t)nbuck * BCAP * 4;
    float* zbuf   = (float*)w;          w += 64 * 128 * 4;
    w = (char*)(((size_t)w + 255) & ~(size_t)255);
    bfu* hs = (bfu*)w;                  w += (size_t)n * 64 * 2;
    w = (char*)(((size_t)w + 255) & ~(size_t)255);
    bfu* hb = (bfu*)w;                  w += (size_t)n * 64 * 2;

    hipMemsetAsync(d_ws, 0, zbytes, stream);

    int gA = (E + CHUNK_A - 1) / CHUNK_A;   // 196
    k_passA<<<gA, TPB, 0, stream>>>(srcv, dstv, E, gcur, staged, nbuck);
    k_passB<<<nbuck, TPB, 0, stream>>>(staged, gcur, csr_off, csr_src, dinv, n, nbuck);

    int gRows = (n + 127) / 128;
    int gNode = (n + 3) / 4;
    // layer 1 gemm: x*W1*dinv -> hs (pure bf16 MFMA)
    k_gemm1<<<gRows, TPB, 0, stream>>>(x, W1, dinv, hs, n);
    // agg1 + fused gemm2: hs -> (agg,relu,+b1) -> *W2*dinv -> hb
    k_agg<true><<<gNode, TPB, 0, stream>>>(hs, csr_off, csr_src, dinv, b1, W2, hb, n);
    // agg2: hb -> (agg,relu,+b2) -> hs
    k_agg<false><<<gNode, TPB, 0, stream>>>(hb, csr_off, csr_src, dinv, b2, nullptr, hs, n);

    int nwaves16 = (n + 15) / 16;
    k_pool<<<(nwaves16 + 3) / 4, TPB, 0, stream>>>(hs, batch, n, gsum, gcnt);
    k_head1<<<32, TPB, 0, stream>>>(gsum, gcnt, fc1w, fc1b, zbuf);
    k_head2<<<1, TPB, 0, stream>>>(zbuf, fc2w, fc2b, (float*)d_out);
}

// Round 9
// 235.587 us; speedup vs baseline: 1.0905x; 1.0905x over previous
//
#include <hip/hip_runtime.h>

// GNN: 2x GCNConv(relu) + mean-pool + MLP head.
// Sizes fixed: N=50000, E=800000, F_IN=256, H=64, NG=64, NC=4.
//
// R9: hs/hb bf16, f32 accumulate. R11: dual-edge packed gather.
// R15: decomposition: pool+head1+head2 = 2.6us, dispatch overhead ~0.
// R16: gemm2 fused into agg1 (free) -> kept.
// R17/R18/R19: agg rewrites converge at 42.5us, FETCH 33MB invariant
//      -> random-line TCC-fill wall (2 lines/edge, bf16-irreducible).
// R20: pure-bf16 gemm1 — absmax UNCHANGED (lo-planes irrelevant). Counters
//      exposed gemm1 = 45us with MFMA 1.2% / VALU 5% / HBM 8.6% / occ 13%:
//      391 blocks (1.5/CU) + barrier-locked K-loop = serialized latency.
// R21 (this round): barrier-free streaming gemm1:
//      - W staged ONCE to 32KB LDS (bf16, [c][k], XOR swizzle), 1 barrier;
//      - A read directly from global per K-step (wave-coalesced 16x128B),
//        converted in-register, MFMA; no barriers in the K-loop;
//      - 64-row blocks -> 782 blocks (~3/CU, 12 waves/CU).

#define TPB 256
#define CHUNK_A 4096
#define BCAP 4608          // per-bucket staging capacity (mean 4096, +8 sigma)

typedef unsigned short bfu;
typedef __attribute__((ext_vector_type(8))) short s16x8;
typedef __attribute__((ext_vector_type(4))) float f32x4;

__device__ __forceinline__ float bf2f(bfu u) {
    union { unsigned u32; float f; } c; c.u32 = ((unsigned)u) << 16; return c.f;
}
__device__ __forceinline__ bfu f2bf(float f) {
    union { float f; unsigned u; } c; c.f = f;
    unsigned r = 0x7FFFu + ((c.u >> 16) & 1u);     // round-to-nearest-even
    return (bfu)((c.u + r) >> 16);
}
__device__ __forceinline__ float blo(unsigned w) {
    union { unsigned u32; float f; } c; c.u32 = w << 16; return c.f;
}
__device__ __forceinline__ float bhi(unsigned w) {
    union { unsigned u32; float f; } c; c.u32 = w & 0xFFFF0000u; return c.f;
}

// ---------------- pass A: chunked bucket staging ----------------
// packed edge: (src<<8) | (dst & 255); requires n <= 65536, nbuck <= 256.

__global__ __launch_bounds__(TPB) void k_passA(const int* __restrict__ srcv,
                                               const int* __restrict__ dstv, int E,
                                               int* __restrict__ gcur,
                                               int* __restrict__ staged, int nbuck) {
    __shared__ int pk[CHUNK_A];
    __shared__ int hist[256];
    __shared__ int ebase[256];
    __shared__ int gbase[256];
    __shared__ int lcur[256];
    int t = threadIdx.x;
    int e0 = blockIdx.x * CHUNK_A;
    int e1 = e0 + CHUNK_A; if (e1 > E) e1 = E;

    hist[t] = 0; lcur[t] = 0;
    __syncthreads();
    for (int i = e0 + t; i < e1; i += TPB) atomicAdd(&hist[dstv[i] >> 8], 1);
    __syncthreads();
    int v = hist[t];
    ebase[t] = v;
    __syncthreads();
    for (int off = 1; off < 256; off <<= 1) {
        int u = (t >= off) ? ebase[t - off] : 0;
        __syncthreads();
        ebase[t] += u;
        __syncthreads();
    }
    ebase[t] -= v;
    if (t < nbuck && v > 0) gbase[t] = t * BCAP + atomicAdd(&gcur[t], v);
    __syncthreads();
    for (int i = e0 + t; i < e1; i += TPB) {
        int d = dstv[i];
        int s = srcv[i];
        int b = d >> 8;
        int r = atomicAdd(&lcur[b], 1);
        pk[ebase[b] + r] = (s << 8) | (d & 255);
    }
    __syncthreads();
    int wave = t >> 6, lane = t & 63;
    for (int b = wave; b < nbuck; b += 4) {
        int c = hist[b];
        int lb = ebase[b];
        int gb = gbase[b];
        for (int j = lane; j < c; j += 64) staged[gb + j] = pk[lb + j];
    }
}

// ---------------- pass B: per-bucket node sort + csr_off + dinv ----------------

__global__ __launch_bounds__(TPB) void k_passB(const int* __restrict__ staged,
                                               const int* __restrict__ gcur,
                                               int* __restrict__ csr_off,
                                               int* __restrict__ csr_src,
                                               float* __restrict__ dinv,
                                               int n, int nbuck) {
    __shared__ int pk[BCAP];
    __shared__ int soff[256];
    __shared__ int hist[256];
    __shared__ int nbase[256];
    __shared__ int cur[256];
    int b = blockIdx.x;
    int n0 = b << 8;
    int n1 = n0 + 256; if (n1 > n) n1 = n;
    int cnt = gcur[b];
    int t = threadIdx.x;

    int cv = (t < nbuck) ? gcur[t] : 0;
    soff[t] = cv;
    hist[t] = 0; cur[t] = 0;
    __syncthreads();
    for (int off = 1; off < 256; off <<= 1) {
        int u = (t >= off) ? soff[t - off] : 0;
        __syncthreads();
        soff[t] += u;
        __syncthreads();
    }
    int base = soff[b] - cnt;   // exclusive prefix at bucket b

    for (int i = t; i < cnt; i += TPB) pk[i] = staged[b * BCAP + i];
    __syncthreads();
    for (int i = t; i < cnt; i += TPB) atomicAdd(&hist[pk[i] & 255], 1);
    __syncthreads();
    int v = hist[t];
    nbase[t] = v;
    __syncthreads();
    for (int off = 1; off < 256; off <<= 1) {
        int u = (t >= off) ? nbase[t - off] : 0;
        __syncthreads();
        nbase[t] += u;
        __syncthreads();
    }
    nbase[t] -= v;
    if (n0 + t < n1) {
        csr_off[n0 + t] = base + nbase[t];
        dinv[n0 + t] = rsqrtf((float)(v + 1));   // +1 self loop
    }
    if (b == nbuck - 1 && t == 0) csr_off[n] = base + cnt;
    __syncthreads();
    for (int i = t; i < cnt; i += TPB) {
        int p = pk[i];
        int dloc = p & 255;
        int r = atomicAdd(&cur[dloc], 1);
        csr_src[base + nbase[dloc] + r] = p >> 8;
    }
}

// ---------------- GEMM1 (R21): barrier-free streaming bf16 MFMA ----------------
// C[r][j] = dinv[r] * sum_k A[r][k] * W[k][j], K=256, 64 cols.
// Block = 64 rows, 4 waves; wave = 16 rows x 64 cols (4 col-tiles 16x16).
// W staged ONCE to LDS as bf16 [c][k] (32KB) with XOR swizzle
// k ^ ((c&15)<<3) (16B granule; uniform 2-way bank access). One barrier.
// K-loop (8 steps of 32): A fragment loaded straight from global
// (lane rl=lane&15 -> row, kg8=(lane>>4)*8 -> k offset; wave-coalesced
// 16 rows x 128B), f32->bf16 in-register, 4 MFMAs. No K-loop barriers;
// waves stream independently (8 independent load rounds in flight).
// C/D map (m89-verified): col=lane&15, row=(lane>>4)*4+reg.

__device__ __forceinline__ int swzW(int c, int k) {
    return c * 256 + (k ^ ((c & 15) << 3));
}

__global__ __launch_bounds__(TPB) void k_gemm1(const float* __restrict__ A,
                                               const float* __restrict__ W,
                                               const float* __restrict__ dinv,
                                               bfu* __restrict__ C, int n) {
    const int K = 256;
    __shared__ __align__(16) ushort Bh[64 * 256];   // 32 KB

    const int t = threadIdx.x;
    const int wave = t >> 6, lane = t & 63;
    const int rbase = blockIdx.x * 64;

    // ---- stage W once: thread t handles col c = t&63, k-range (t>>6)*64 ----
    {
        int c = t & 63;
        int kg = (t >> 6) << 6;   // 64 k's per wave
#pragma unroll
        for (int q = 0; q < 8; q++) {
            int k8 = kg + q * 8;
            ushort4 h0, h1;
#pragma unroll
            for (int j = 0; j < 4; j++) ((bfu*)&h0)[j] = f2bf(W[(size_t)(k8 + j) * 64 + c]);
#pragma unroll
            for (int j = 0; j < 4; j++) ((bfu*)&h1)[j] = f2bf(W[(size_t)(k8 + 4 + j) * 64 + c]);
            *(ushort4*)&Bh[swzW(c, k8)]     = h0;
            *(ushort4*)&Bh[swzW(c, k8) + 4] = h1;   // same 8-block, contiguous
        }
    }
    __syncthreads();   // the only barrier

    const int rl = lane & 15;            // row within tile / col within tile
    const int kg8 = (lane >> 4) << 3;    // k offset of this lane group
    int r0 = rbase + wave * 16 + rl;
    const float* arow = A + (size_t)(r0 < n ? r0 : (n - 1)) * K;

    f32x4 acc[4];
#pragma unroll
    for (int j = 0; j < 4; j++) acc[j] = {0.f, 0.f, 0.f, 0.f};

#pragma unroll
    for (int ks = 0; ks < 8; ks++) {
        int k0 = ks * 32 + kg8;
        float4 xa = *(const float4*)(arow + k0);
        float4 xb = *(const float4*)(arow + k0 + 4);
        s16x8 af;
        ((bfu*)&af)[0] = f2bf(xa.x);
        ((bfu*)&af)[1] = f2bf(xa.y);
        ((bfu*)&af)[2] = f2bf(xa.z);
        ((bfu*)&af)[3] = f2bf(xa.w);
        ((bfu*)&af)[4] = f2bf(xb.x);
        ((bfu*)&af)[5] = f2bf(xb.y);
        ((bfu*)&af)[6] = f2bf(xb.z);
        ((bfu*)&af)[7] = f2bf(xb.w);
#pragma unroll
        for (int ct = 0; ct < 4; ct++) {
            s16x8 bf = *(const s16x8*)&Bh[swzW(ct * 16 + rl, k0)];
            acc[ct] = __builtin_amdgcn_mfma_f32_16x16x32_bf16(af, bf, acc[ct], 0, 0, 0);
        }
    }

    // ---- epilogue: col = lane&15, row = (lane>>4)*4 + reg ----
    const int rq = (lane >> 4) << 2;
#pragma unroll
    for (int reg = 0; reg < 4; reg++) {
        int r = rbase + wave * 16 + rq + reg;
        if (r < n) {
            float d = dinv[r];
#pragma unroll
            for (int ct = 0; ct < 4; ct++) {
                C[(size_t)r * 64 + ct * 16 + rl] = f2bf(acc[ct][reg] * d);
            }
        }
    }
}

// ---------------- Aggregation (R19): wide row gather (dwordx4) ----------------
// Wave = 1 node. Lane map: g = lane>>3 (row slot 0..7), c = lane&7
// (8-feature chunk). One dwordx4 gather = 8 neighbor rows x 128B
// (16B/lane). Index load csr_src[p0+base+g]: broadcast in 8-lane groups,
// NO shfl. Feature totals via 3 shfl_xor rounds once per node.
// FUSE: per-wave 64x64 W2 matmul on the relu'd row (gemm2 fusion, R16).

__device__ __forceinline__ void acc_u4(float* acc, uint4 q) {
    acc[0] += blo(q.x); acc[1] += bhi(q.x);
    acc[2] += blo(q.y); acc[3] += bhi(q.y);
    acc[4] += blo(q.z); acc[5] += bhi(q.z);
    acc[6] += blo(q.w); acc[7] += bhi(q.w);
}

template <bool FUSE>
__global__ __launch_bounds__(TPB) void k_agg(const bfu* __restrict__ hs,
                                             const int* __restrict__ csr_off,
                                             const int* __restrict__ csr_src,
                                             const float* __restrict__ dinv,
                                             const float* __restrict__ bias,
                                             const float* __restrict__ W2,
                                             bfu* __restrict__ out, int n) {
    __shared__ float rowbuf[4][64];
    int wv = threadIdx.x >> 6;
    int node = blockIdx.x * 4 + wv;
    int lane = threadIdx.x & 63;
    int g = lane >> 3;             // row slot within batch
    int c = lane & 7;              // feature chunk (feats c*8 .. c*8+7)
    if (node >= n) return;
    int p0 = csr_off[node];
    int p1 = csr_off[node + 1];
    int deg = p1 - p0;
    float d = dinv[node];          // issue early, needed late

    // self row (hot line), added once after the cross-lane reduction
    uint4 selfv = *(const uint4*)(hs + (size_t)node * 64 + c * 8);

    float acc[8];
#pragma unroll
    for (int j = 0; j < 8; j++) acc[j] = 0.f;

    for (int base = 0; base < deg; base += 16) {
        int rem = deg - base;
        int li0 = p0 + base + g;
        if (rem > 8) {
            // slots 0..7 all valid; slots 8..15 predicated
            int li1 = li0 + 8;
            int idx0 = csr_src[li0];
            int idx1 = csr_src[li1 < p1 ? li1 : p0];
            bool v1 = (8 + g) < rem;
            uint4 q0 = *(const uint4*)(hs + (size_t)idx0 * 64 + c * 8);
            uint4 q1 = *(const uint4*)(hs + (size_t)(v1 ? idx1 : node) * 64 + c * 8);
            if (!v1) q1 = make_uint4(0u, 0u, 0u, 0u);
            acc_u4(acc, q0);
            acc_u4(acc, q1);
        } else {
            bool v0 = g < rem;
            int idx0 = csr_src[li0 < p1 ? li0 : p0];
            uint4 q0 = *(const uint4*)(hs + (size_t)(v0 ? idx0 : node) * 64 + c * 8);
            if (!v0) q0 = make_uint4(0u, 0u, 0u, 0u);
            acc_u4(acc, q0);
        }
    }

    // reduce across row-slot groups (lane bits 3,4,5)
#pragma unroll
    for (int j = 0; j < 8; j++) {
        acc[j] += __shfl_xor(acc[j], 8);
        acc[j] += __shfl_xor(acc[j], 16);
        acc[j] += __shfl_xor(acc[j], 32);
    }
    // self loop (each lane keeps a consistent replicated copy)
    acc_u4(acc, selfv);

    float4 b0 = *(const float4*)&bias[c * 8];
    float4 b1 = *(const float4*)&bias[c * 8 + 4];
    float v[8];
    v[0] = fmaxf(d * acc[0] + b0.x, 0.f);
    v[1] = fmaxf(d * acc[1] + b0.y, 0.f);
    v[2] = fmaxf(d * acc[2] + b0.z, 0.f);
    v[3] = fmaxf(d * acc[3] + b0.w, 0.f);
    v[4] = fmaxf(d * acc[4] + b1.x, 0.f);
    v[5] = fmaxf(d * acc[5] + b1.y, 0.f);
    v[6] = fmaxf(d * acc[6] + b1.z, 0.f);
    v[7] = fmaxf(d * acc[7] + b1.w, 0.f);

    if (!FUSE) {
        if (g == 0) {   // lanes 0..7 write the 128B row
            uint4 o;
            o.x = (unsigned)f2bf(v[0]) | ((unsigned)f2bf(v[1]) << 16);
            o.y = (unsigned)f2bf(v[2]) | ((unsigned)f2bf(v[3]) << 16);
            o.z = (unsigned)f2bf(v[4]) | ((unsigned)f2bf(v[5]) << 16);
            o.w = (unsigned)f2bf(v[6]) | ((unsigned)f2bf(v[7]) << 16);
            *(uint4*)(out + (size_t)node * 64 + c * 8) = o;
        }
    } else {
        // fused gemm2: out[node][lane] = f2bf(d * sum_k row[k] * W2[k][lane])
        if (g == 0) {
            *(float4*)&rowbuf[wv][c * 8]     = make_float4(v[0], v[1], v[2], v[3]);
            *(float4*)&rowbuf[wv][c * 8 + 4] = make_float4(v[4], v[5], v[6], v[7]);
        }
        __builtin_amdgcn_wave_barrier();   // ds_write before ds_read (same wave: HW in-order)
        float a = 0.f;
#pragma unroll 16
        for (int k = 0; k < 64; k++) a += rowbuf[wv][k] * W2[k * 64 + lane];
        out[(size_t)node * 64 + lane] = f2bf(d * a);
    }
}

// ---------------- Pool: sorted batch; uniform-chunk fast path (bf16 reads) ----------------

__global__ __launch_bounds__(TPB) void k_pool(const bfu* __restrict__ h,
                                              const int* __restrict__ batch, int n,
                                              float* __restrict__ gsum,
                                              int* __restrict__ gcnt) {
    const int CH = 16;
    int wid = blockIdx.x * 4 + (threadIdx.x >> 6);
    int lane = threadIdx.x & 63;
    int i0 = wid * CH;
    if (i0 >= n) return;
    int i1 = i0 + CH; if (i1 > n) i1 = n;
    int g0 = batch[i0];
    int g1 = batch[i1 - 1];
    if (g0 == g1) {
        float acc = 0.f;
#pragma unroll
        for (int i = 0; i < CH; i++) {
            int idx = i0 + i;
            if (idx < i1) acc += bf2f(h[(size_t)idx * 64 + lane]);
        }
        atomicAdd(&gsum[g0 * 64 + lane], acc);
        if (lane == 0) atomicAdd(&gcnt[g0], i1 - i0);
    } else {
        int cur = g0;
        float acc = 0.f;
        int cnt = 0;
        for (int i = i0; i < i1; i++) {
            int g = batch[i];
            if (g != cur) {
                atomicAdd(&gsum[cur * 64 + lane], acc);
                if (lane == 0) atomicAdd(&gcnt[cur], cnt);
                acc = 0.f; cnt = 0; cur = g;
            }
            acc += bf2f(h[(size_t)i * 64 + lane]);
            cnt++;
        }
        atomicAdd(&gsum[cur * 64 + lane], acc);
        if (lane == 0) atomicAdd(&gcnt[cur], cnt);
    }
}

// ---------------- Head, stage 1 ----------------

__global__ __launch_bounds__(TPB) void k_head1(const float* __restrict__ gsum,
                                               const int* __restrict__ gcnt,
                                               const float* __restrict__ fc1w,
                                               const float* __restrict__ fc1b,
                                               float* __restrict__ z) {
    int t = threadIdx.x;
    int g = blockIdx.x * 2 + (t >> 7);
    int o = t & 127;
    int c = gcnt[g]; if (c < 1) c = 1;
    float inv = 1.0f / (float)c;
    float a = fc1b[o];
#pragma unroll 16
    for (int j = 0; j < 64; j++) {
        float pj = gsum[g * 64 + j] * inv;
        a += pj * fc1w[j * 128 + o];
    }
    z[g * 128 + o] = fmaxf(a, 0.f);
}

// ---------------- Head, stage 2 ----------------

__global__ __launch_bounds__(TPB) void k_head2(const float* __restrict__ z,
                                               const float* __restrict__ fc2w,
                                               const float* __restrict__ fc2b,
                                               float* __restrict__ out) {
    int t = threadIdx.x;
    int g = t >> 2, c = t & 3;
    float a = fc2b[c];
#pragma unroll 16
    for (int o = 0; o < 128; o++) a += z[g * 128 + o] * fc2w[o * 4 + c];
    out[t] = a;
}

// ---------------- launch ----------------

extern "C" void kernel_launch(void* const* d_in, const int* in_sizes, int n_in,
                              void* d_out, int out_size, void* d_ws, size_t ws_size,
                              hipStream_t stream) {
    const float* x    = (const float*)d_in[0];
    const int*   ei   = (const int*)d_in[1];
    const int*   batch= (const int*)d_in[2];
    const float* W1   = (const float*)d_in[3];
    const float* b1   = (const float*)d_in[4];
    const float* W2   = (const float*)d_in[5];
    const float* b2   = (const float*)d_in[6];
    const float* fc1w = (const float*)d_in[7];
    const float* fc1b = (const float*)d_in[8];
    const float* fc2w = (const float*)d_in[9];
    const float* fc2b = (const float*)d_in[10];

    const int n = in_sizes[2];        // 50000
    const int E = in_sizes[1] / 2;    // 800000
    const int* srcv = ei;
    const int* dstv = ei + E;
    const int nbuck = (n + 255) >> 8; // 196 (must be <= 256)

    // workspace carve; zeroed region contiguous at front
    char* w = (char*)d_ws;
    int*   gcur   = (int*)w;            w += 256 * 4;
    int*   gcnt   = (int*)w;            w += 64 * 4;
    float* gsum   = (float*)w;          w += 64 * 64 * 4;
    size_t zbytes = (size_t)w - (size_t)d_ws;
    int*   csr_off= (int*)w;            w += (size_t)(n + 1) * 4;
    float* dinv   = (float*)w;          w += (size_t)n * 4;
    int*   csr_src= (int*)w;            w += (size_t)E * 4;
    int*   staged = (int*)w;            w += (size_t)nbuck * BCAP * 4;
    float* zbuf   = (float*)w;          w += 64 * 128 * 4;
    w = (char*)(((size_t)w + 255) & ~(size_t)255);
    bfu* hs = (bfu*)w;                  w += (size_t)n * 64 * 2;
    w = (char*)(((size_t)w + 255) & ~(size_t)255);
    bfu* hb = (bfu*)w;                  w += (size_t)n * 64 * 2;

    hipMemsetAsync(d_ws, 0, zbytes, stream);

    int gA = (E + CHUNK_A - 1) / CHUNK_A;   // 196
    k_passA<<<gA, TPB, 0, stream>>>(srcv, dstv, E, gcur, staged, nbuck);
    k_passB<<<nbuck, TPB, 0, stream>>>(staged, gcur, csr_off, csr_src, dinv, n, nbuck);

    int gRows = (n + 63) / 64;   // 782
    int gNode = (n + 3) / 4;
    // layer 1 gemm: x*W1*dinv -> hs (barrier-free streaming bf16 MFMA)
    k_gemm1<<<gRows, TPB, 0, stream>>>(x, W1, dinv, hs, n);
    // agg1 + fused gemm2: hs -> (agg,relu,+b1) -> *W2*dinv -> hb
    k_agg<true><<<gNode, TPB, 0, stream>>>(hs, csr_off, csr_src, dinv, b1, W2, hb, n);
    // agg2: hb -> (agg,relu,+b2) -> hs
    k_agg<false><<<gNode, TPB, 0, stream>>>(hb, csr_off, csr_src, dinv, b2, nullptr, hs, n);

    int nwaves16 = (n + 15) / 16;
    k_pool<<<(nwaves16 + 3) / 4, TPB, 0, stream>>>(hs, batch, n, gsum, gcnt);
    k_head1<<<32, TPB, 0, stream>>>(gsum, gcnt, fc1w, fc1b, zbuf);
    k_head2<<<1, TPB, 0, stream>>>(zbuf, fc2w, fc2b, (float*)d_out);
}